// Round 7
// baseline (116.334 us; speedup 1.0000x reference)
//
#include <hip/hip_runtime.h>
#include <stdint.h>

#define NC13 507
#define NC26 2028
#define NC52 8112
#define NCAND 10647
#define KSEL 512
#define POOLCAP 2048
#define SUPW 17   // padded SUP row stride (17 coprime 32 -> conflict-free)
#define CMW 17    // padded class-mask stride
#define DECB 12   // decode blocks per image (8 s52 + 2 s26 + 2 s13)

// ---------------------------------------------------------------------------
// Candidate key, recomputed on demand (never materialized in HBM).
//   valid (xo>0):  bit63 | float_bits(xo)<<32 | (0x3FFF - n)
//   invalid     :  (0x3FFF - n)
// Descending key order == (conf desc, index asc) of the reference exactly.
// ---------------------------------------------------------------------------
__device__ __forceinline__ unsigned long long cand_key(
    int i, int b,
    const float* __restrict__ in13,
    const float* __restrict__ in26,
    const float* __restrict__ in52)
{
    const float* in; int HW, base;
    if (i < NC13)              { in = in13; HW = 169;  base = 0; }
    else if (i < NC13 + NC26)  { in = in26; HW = 676;  base = NC13; }
    else                       { in = in52; HW = 2704; base = NC13 + NC26; }
    const int within = i - base;
    const int a  = within / HW;
    const int hw = within - a * HW;
    const float xo = in[((size_t)b * 255 + (size_t)a * 85 + 4) * HW + hw];
    const int n = base + hw * 3 + a;     // reference candidate index
    const unsigned long long low = (unsigned long long)(0x3FFFu - (unsigned)n);
    return (xo > 0.0f)
        ? ((1ull << 63) | ((unsigned long long)__float_as_uint(xo) << 32) | low)
        : low;
}

struct SelShared {
    unsigned int hist[4096];
    unsigned long long pool[POOLCAP];
    unsigned int cnt;
    unsigned long long prefix;
    unsigned long long tmin;
    int krem, shift, brk, V;
};

// ---------------------------------------------------------------------------
// Box decode (identical arithmetic to verified rounds: absmax 0.0).
// ---------------------------------------------------------------------------
__device__ __forceinline__ void decode_write(
    float* __restrict__ o, int w, int h, float ts,
    float tx, float ty, float tw, float th, float xo,
    float aw, float ah, int cls)
{
    const float sx   = 1.0f / (1.0f + expf(-tx));
    const float sy   = 1.0f / (1.0f + expf(-ty));
    const float conf = 1.0f / (1.0f + expf(-xo));
    const float cx = ((float)w + sx) * ts;
    const float cy = ((float)h + sy) * ts;
    const float bw = aw * expf(tw);
    const float bh = ah * expf(th);
    o[0] = cx - bw * 0.5f; o[1] = cy - bh * 0.5f;
    o[2] = cx + bw * 0.5f; o[3] = cy + bh * 0.5f;
    o[4] = conf; o[5] = (float)cls;
}

// float4 decode of 4 consecutive candidates (hw..hw+3), batched class loads
// with 1-batch-ahead prefetch for deep memory-level parallelism.
__device__ __forceinline__ void decode4(
    const float* __restrict__ in, const float* __restrict__ anch,
    int b, int a, int hw, int HW, int Hdim, float ts, int base,
    float* __restrict__ boxesAll)
{
    const int HW4 = HW >> 2;
    const float4* p4 = reinterpret_cast<const float4*>(
        in + ((size_t)b * 255 + (size_t)a * 85) * HW + hw);

    // box channels issued first; latency hides under the class batches
    const float4 txv = p4[0];
    const float4 tyv = p4[(size_t)HW4];
    const float4 twv = p4[(size_t)2 * HW4];
    const float4 thv = p4[(size_t)3 * HW4];
    const float4 xov = p4[(size_t)4 * HW4];

    float4 best = make_float4(-INFINITY, -INFINITY, -INFINITY, -INFINITY);
    int bx = 0, by = 0, bz = 0, bw4 = 0;

    float4 vb[8];
    #pragma unroll
    for (int j = 0; j < 8; ++j) vb[j] = p4[(size_t)(5 + j) * HW4];
    for (int cb = 0; cb < 10; ++cb) {
        float4 vn[8];
        if (cb < 9) {
            #pragma unroll
            for (int j = 0; j < 8; ++j) vn[j] = p4[(size_t)(13 + cb * 8 + j) * HW4];
        }
        #pragma unroll
        for (int j = 0; j < 8; ++j) {
            const int c = cb * 8 + j;          // strict > == first-max (jnp.argmax)
            if (vb[j].x > best.x) { best.x = vb[j].x; bx = c; }
            if (vb[j].y > best.y) { best.y = vb[j].y; by = c; }
            if (vb[j].z > best.z) { best.z = vb[j].z; bz = c; }
            if (vb[j].w > best.w) { best.w = vb[j].w; bw4 = c; }
        }
        #pragma unroll
        for (int j = 0; j < 8; ++j) vb[j] = vn[j];
    }

    const float aw = anch[2 * a], ah = anch[2 * a + 1];
    const int i0 = base + a * HW + hw;
    float* o = boxesAll + ((size_t)b * NCAND + i0) * 6;
    {
        const int h = hw / Hdim, w = hw - h * Hdim;
        decode_write(o, w, h, ts, txv.x, tyv.x, twv.x, thv.x, xov.x, aw, ah, bx);
    }
    {
        const int h = (hw + 1) / Hdim, w = (hw + 1) - h * Hdim;
        decode_write(o + 6, w, h, ts, txv.y, tyv.y, twv.y, thv.y, xov.y, aw, ah, by);
    }
    {
        const int h = (hw + 2) / Hdim, w = (hw + 2) - h * Hdim;
        decode_write(o + 12, w, h, ts, txv.z, tyv.z, twv.z, thv.z, xov.z, aw, ah, bz);
    }
    {
        const int h = (hw + 3) / Hdim, w = (hw + 3) - h * Hdim;
        decode_write(o + 18, w, h, ts, txv.w, tyv.w, twv.w, thv.w, xov.w, aw, ah, bw4);
    }
}

// ---------------------------------------------------------------------------
// Fused kernel, 256-thread blocks:
//   blocks [0,B):            per-image top-512 radix select (exact)
//   blocks [B, B+DECB*B):    streaming float4/scalar decode of all candidates
// ---------------------------------------------------------------------------
__global__ void main_kernel(
    const float* __restrict__ in13,
    const float* __restrict__ in26,
    const float* __restrict__ in52,
    const float* __restrict__ a13,
    const float* __restrict__ a26,
    const float* __restrict__ a52,
    int B,
    int* __restrict__ selidx,
    int* __restrict__ selv,
    float* __restrict__ boxesAll)
{
    __shared__ __align__(16) char smem_raw[sizeof(SelShared)];
    const int bid = blockIdx.x;
    const int tid = threadIdx.x;

    if (bid < B) {
        // ================= SELECT (one block per image) =================
        SelShared& S = *reinterpret_cast<SelShared*>(smem_raw);
        const int b = bid;
        if (tid == 0) { S.cnt = 0; S.prefix = 0; S.krem = KSEL; S.shift = 52; S.brk = 0; S.V = 0; }
        __syncthreads();

        for (int i = tid; i < NCAND; i += 256) {
            const unsigned long long k = cand_key(i, b, in13, in26, in52);
            const unsigned long long bal = __ballot((k >> 63) != 0ull);
            if ((tid & 63) == 0) atomicAdd(&S.V, (int)__popcll(bal));
        }
        __syncthreads();
        const bool include = (S.V < KSEL);   // degenerate fallback only

        while (true) {
            const int shift = S.shift;
            const unsigned long long prefix = S.prefix;
            const int krem = S.krem;
            __syncthreads();
            for (int i = tid; i < 4096; i += 256) S.hist[i] = 0;
            __syncthreads();
            for (int i = tid; i < NCAND; i += 256) {
                const unsigned long long k = cand_key(i, b, in13, in26, in52);
                const bool part = include || ((k >> 63) != 0ull);
                const bool ok = part &&
                    ((shift == 52) || ((k >> (shift + 12)) == prefix));
                if (ok) atomicAdd(&S.hist[(unsigned)((k >> shift) & 0xFFFull)], 1u);
            }
            __syncthreads();
            if (tid < 64) {
                unsigned int s = 0;
                for (int q = 0; q < 64; ++q) s += S.hist[tid * 64 + q];
                unsigned int suf = s;
                for (int off = 1; off < 64; off <<= 1) {
                    const unsigned int v = __shfl_down(suf, off);
                    if (tid + off < 64) suf += v;
                }
                const unsigned long long ball = __ballot(suf >= (unsigned)krem);
                const int lstar = 63 - __clzll(ball);
                const unsigned int base = (lstar < 63) ? __shfl(suf, lstar + 1) : 0u;
                const unsigned int wv = S.hist[lstar * 64 + (63 - tid)];
                unsigned int pv = wv;
                for (int off = 1; off < 64; off <<= 1) {
                    const unsigned int v = __shfl_up(pv, off);
                    if (tid >= (unsigned)off) pv += v;
                }
                const unsigned long long b2 = __ballot(base + pv >= (unsigned)krem);
                const int mstar = __ffsll(b2) - 1;
                const unsigned int pvm = __shfl(pv, mstar);
                const unsigned int wvm = __shfl(wv, mstar);
                if (tid == 0) {
                    const int dstar = lstar * 64 + (63 - mstar);
                    const unsigned long long np = (prefix << 12) | (unsigned long long)dstar;
                    const int Albl = (int)(base + pvm - wvm);
                    const int Cpool = (KSEL - krem) + Albl + (int)wvm;
                    S.prefix = np;
                    S.krem = krem - Albl;
                    if (Cpool <= POOLCAP || shift == 4) {
                        S.brk = 1;
                        S.tmin = np << shift;
                    } else {
                        S.shift = shift - 12;
                    }
                }
            }
            __syncthreads();
            if (S.brk) break;
        }
        const unsigned long long tmin = S.tmin;

        for (int i = tid; i < NCAND; i += 256) {
            const unsigned long long k = cand_key(i, b, in13, in26, in52);
            if (k >= tmin) {
                const unsigned int p = atomicAdd(&S.cnt, 1u);
                if (p < POOLCAP) S.pool[p] = k;
            }
        }
        __syncthreads();
        const int C = ((int)S.cnt < POOLCAP) ? (int)S.cnt : POOLCAP;

        for (int p = tid; p < C; p += 256) {
            const unsigned long long k = S.pool[p];
            int r = 0;
            for (int j = 0; j < C; ++j) r += (S.pool[j] > k) ? 1 : 0;
            if (r < KSEL) {
                const int idx = 0x3FFF - (int)(k & 0x3FFFull);
                selidx[(size_t)b * KSEL + r] = idx;
                selv[(size_t)b * KSEL + r]   = (int)(k >> 63);
            }
        }
        return;
    }

    // ================= DECODE =================
    const int d = bid - B;
    const int b = d / DECB;
    const int role = d - b * DECB;

    if (role < 8) {                      // s52: 2028 float4-groups over 8 blocks
        const int idx4 = role * 256 + tid;
        if (idx4 < 3 * 676) {
            const int a = idx4 / 676, g = idx4 - a * 676;
            decode4(in52, a52, b, a, g * 4, 2704, 52, 8.f, NC13 + NC26, boxesAll);
        }
    } else if (role < 10) {              // s26: 507 float4-groups over 2 blocks
        const int idx4 = (role - 8) * 256 + tid;
        if (idx4 < 3 * 169) {
            const int a = idx4 / 169, g = idx4 - a * 169;
            decode4(in26, a26, b, a, g * 4, 676, 26, 16.f, NC13, boxesAll);
        }
    } else {                             // s13: 507 scalar over 2 blocks
        const int idx = (role - 10) * 256 + tid;
        if (idx < NC13) {
            const int HW = 169;
            const int a = idx / HW, hw = idx - a * HW;
            const int h = hw / 13, w = hw - h * 13;
            const float* p = in13 + ((size_t)b * 255 + (size_t)a * 85) * HW + hw;
            const float tx = p[0];
            const float ty = p[(size_t)HW];
            const float tw = p[(size_t)2 * HW];
            const float th = p[(size_t)3 * HW];
            const float xo = p[(size_t)4 * HW];
            float best = -INFINITY; int bi = 0;
            float vb[8];
            #pragma unroll
            for (int j = 0; j < 8; ++j) vb[j] = p[(size_t)(5 + j) * HW];
            for (int cb = 0; cb < 10; ++cb) {
                float vn[8];
                if (cb < 9) {
                    #pragma unroll
                    for (int j = 0; j < 8; ++j) vn[j] = p[(size_t)(13 + cb * 8 + j) * HW];
                }
                #pragma unroll
                for (int j = 0; j < 8; ++j) {
                    const int c = cb * 8 + j;
                    if (vb[j] > best) { best = vb[j]; bi = c; }
                }
                #pragma unroll
                for (int j = 0; j < 8; ++j) vb[j] = vn[j];
            }
            const int i = a * HW + hw;   // base 0
            decode_write(boxesAll + ((size_t)b * NCAND + i) * 6, w, h, 32.f,
                         tx, ty, tw, th, xo, a13[2 * a], a13[2 * a + 1], bi);
        }
    }
}

// ---------------------------------------------------------------------------
// NMS kernel (unchanged from the verified version).
// ---------------------------------------------------------------------------
__global__ __launch_bounds__(512) void nms_kernel(
    const float* __restrict__ boxesAll,
    const int* __restrict__ selidx,
    const int* __restrict__ selv,
    float* __restrict__ out)
{
    __shared__ float X1[KSEL], Y1[KSEL], X2[KSEL], Y2[KSEL], AR[KSEL];
    __shared__ int CLS[KSEL];
    __shared__ unsigned int CM[80 * CMW];
    __shared__ unsigned int SUP[KSEL * SUPW];
    __shared__ unsigned int KEEP[16];
    __shared__ int shV;

    const int b = blockIdx.x;
    const int tid = threadIdx.x;

    const int n = selidx[(size_t)b * KSEL + tid];
    int base, HW;
    if (n < NC13)             { base = 0;           HW = 169; }
    else if (n < NC13 + NC26) { base = NC13;        HW = 676; }
    else                      { base = NC13 + NC26; HW = 2704; }
    const int within = n - base;
    const int hw = within / 3, a = within - 3 * hw;
    const int i = base + a * HW + hw;
    const float* src = boxesAll + ((size_t)b * NCAND + i) * 6;
    const float x1 = src[0], y1 = src[1], x2 = src[2], y2 = src[3];
    const float conf = src[4], clsf = src[5];
    const float ar = (x2 - x1) * (y2 - y1);
    const int ci = (int)clsf;
    X1[tid] = x1; Y1[tid] = y1; X2[tid] = x2; Y2[tid] = y2;
    AR[tid] = ar; CLS[tid] = ci;
    const int v = selv[(size_t)b * KSEL + tid];
    if (tid == 0) shV = 0;
    for (int q = tid; q < 80 * CMW; q += KSEL) CM[q] = 0;
    __syncthreads();

    atomicOr(&CM[ci * CMW + (tid >> 5)], 1u << (tid & 31));
    const unsigned long long bal = __ballot(v != 0);
    if ((tid & 63) == 0) atomicAdd(&shV, __popcll(bal));
    __syncthreads();

    for (int wj = 0; wj < 16; ++wj) {
        unsigned int m = CM[ci * CMW + wj];
        unsigned int bits = 0;
        while (m) {
            const int bit = __ffs(m) - 1;
            m &= m - 1;
            const int j = wj * 32 + bit;
            const float iw = fminf(x2, X2[j]) - fmaxf(x1, X1[j]);
            const float ih = fminf(y2, Y2[j]) - fmaxf(y1, Y1[j]);
            if (iw > 0.0f && ih > 0.0f) {
                const float inter = iw * ih;
                if (inter > 0.3f * (ar + AR[j] - inter + 1e-9f))
                    bits |= (1u << bit);
            }
        }
        SUP[tid * SUPW + wj] = bits;
    }
    __syncthreads();

    if (tid < 64) {
        const int V = shV;
        unsigned int keepw = 0;       // lanes 0..15 hold the 512-bit keep mask
        unsigned int buf[16];
        #pragma unroll
        for (int r = 0; r < 16; ++r)
            buf[r] = (tid < 16) ? SUP[r * SUPW + tid] : 0u;
        for (int g = 0; g < 32; ++g) {
            unsigned int nbuf[16] = {0};
            if (g < 31) {
                #pragma unroll
                for (int r = 0; r < 16; ++r)
                    nbuf[r] = (tid < 16) ? SUP[((g + 1) * 16 + r) * SUPW + tid] : 0u;
            }
            #pragma unroll
            for (int r = 0; r < 16; ++r) {
                const int ii = g * 16 + r;
                const bool anysup = __any((keepw & buf[r]) != 0u);
                const bool ki = (ii < V) && !anysup;
                if (ki && tid == (ii >> 5)) keepw |= (1u << (ii & 31));
            }
            #pragma unroll
            for (int r = 0; r < 16; ++r) buf[r] = nbuf[r];
        }
        if (tid < 16) KEEP[tid] = keepw;
    }
    __syncthreads();

    const float kf = ((KEEP[tid >> 5] >> (tid & 31)) & 1u) ? 1.0f : 0.0f;
    float* dst = out + ((size_t)b * KSEL + tid) * 7;
    dst[0] = x1; dst[1] = y1; dst[2] = x2;
    dst[3] = y2; dst[4] = conf; dst[5] = clsf;
    dst[6] = kf;
}

// ---------------------------------------------------------------------------
extern "C" void kernel_launch(void* const* d_in, const int* in_sizes, int n_in,
                              void* d_out, int out_size, void* d_ws, size_t ws_size,
                              hipStream_t stream)
{
    (void)n_in; (void)out_size; (void)ws_size;
    const float* in13 = (const float*)d_in[0];
    const float* in26 = (const float*)d_in[1];
    const float* in52 = (const float*)d_in[2];
    const float* a13  = (const float*)d_in[3];
    const float* a26  = (const float*)d_in[4];
    const float* a52  = (const float*)d_in[5];
    float* out = (float*)d_out;
    const int B = in_sizes[0] / (255 * 169);

    char* w = (char*)d_ws;
    int* selidx = (int*)w;  w += ((size_t)B * KSEL * sizeof(int) + 255) & ~(size_t)255;
    int* selv   = (int*)w;  w += ((size_t)B * KSEL * sizeof(int) + 255) & ~(size_t)255;
    float* boxesAll = (float*)w;
    w += ((size_t)B * NCAND * 6 * sizeof(float) + 255) & ~(size_t)255;

    main_kernel<<<dim3(B * (1 + DECB)), 256, 0, stream>>>(
        in13, in26, in52, a13, a26, a52, B, selidx, selv, boxesAll);
    nms_kernel<<<dim3(B), 512, 0, stream>>>(boxesAll, selidx, selv, out);
}

// Round 8
// 84.221 us; speedup vs baseline: 1.3813x; 1.3813x over previous
//
#include <hip/hip_runtime.h>
#include <stdint.h>

#define NC13 507
#define NC26 2028
#define NC52 8112
#define NCAND 10647
#define KSEL 512
#define POOLCAP 768
#define POOLTGT 640
#define SUPW 17   // padded SUP row stride (17 coprime 32 -> conflict-free)
#define CMW 17    // padded class-mask stride
#define DECB 6    // decode blocks per image (4 s52 + 1 s26 + 1 s13)

// ---------------------------------------------------------------------------
// Candidate key, recomputed on demand (never materialized in HBM).
//   valid (xo>0):  bit63 | float_bits(xo)<<32 | (0x3FFF - n)
//   invalid     :  (0x3FFF - n)
// Descending key order == (conf desc, index asc) of the reference exactly.
// ---------------------------------------------------------------------------
__device__ __forceinline__ unsigned long long cand_key(
    int i, int b,
    const float* __restrict__ in13,
    const float* __restrict__ in26,
    const float* __restrict__ in52)
{
    const float* in; int HW, base;
    if (i < NC13)              { in = in13; HW = 169;  base = 0; }
    else if (i < NC13 + NC26)  { in = in26; HW = 676;  base = NC13; }
    else                       { in = in52; HW = 2704; base = NC13 + NC26; }
    const int within = i - base;
    const int a  = within / HW;
    const int hw = within - a * HW;
    const float xo = in[((size_t)b * 255 + (size_t)a * 85 + 4) * HW + hw];
    const int n = base + hw * 3 + a;     // reference candidate index
    const unsigned long long low = (unsigned long long)(0x3FFFu - (unsigned)n);
    return (xo > 0.0f)
        ? ((1ull << 63) | ((unsigned long long)__float_as_uint(xo) << 32) | low)
        : low;
}

struct SelShared {
    unsigned int hist[4096];
    unsigned long long pool[POOLCAP];
    unsigned int cnt;
    unsigned long long prefix;
    unsigned long long tmin;
    int krem, shift, brk, V;
};

// ---------------------------------------------------------------------------
// Box decode (identical arithmetic to verified rounds: absmax 0.0).
// ---------------------------------------------------------------------------
__device__ __forceinline__ void decode_write(
    float* __restrict__ o, int w, int h, float ts,
    float tx, float ty, float tw, float th, float xo,
    float aw, float ah, int cls)
{
    const float sx   = 1.0f / (1.0f + expf(-tx));
    const float sy   = 1.0f / (1.0f + expf(-ty));
    const float conf = 1.0f / (1.0f + expf(-xo));
    const float cx = ((float)w + sx) * ts;
    const float cy = ((float)h + sy) * ts;
    const float bw = aw * expf(tw);
    const float bh = ah * expf(th);
    o[0] = cx - bw * 0.5f; o[1] = cy - bh * 0.5f;
    o[2] = cx + bw * 0.5f; o[3] = cy + bh * 0.5f;
    o[4] = conf; o[5] = (float)cls;
}

// float4 decode of 4 consecutive candidates (hw..hw+3); class loads in
// batches of 4 with 1-batch-ahead prefetch (32 data VGPRs -> no spill).
__device__ __forceinline__ void decode4(
    const float* __restrict__ in, const float* __restrict__ anch,
    int b, int a, int hw, int HW, int Hdim, float ts, int base,
    float* __restrict__ boxesAll)
{
    const int HW4 = HW >> 2;
    const float4* p4 = reinterpret_cast<const float4*>(
        in + ((size_t)b * 255 + (size_t)a * 85) * HW + hw);

    const float4 txv = p4[0];
    const float4 tyv = p4[(size_t)HW4];
    const float4 twv = p4[(size_t)2 * HW4];
    const float4 thv = p4[(size_t)3 * HW4];
    const float4 xov = p4[(size_t)4 * HW4];

    float4 best = make_float4(-INFINITY, -INFINITY, -INFINITY, -INFINITY);
    int bx = 0, by = 0, bz = 0, bw4 = 0;

    float4 vb[4];
    #pragma unroll
    for (int j = 0; j < 4; ++j) vb[j] = p4[(size_t)(5 + j) * HW4];
    for (int cb = 0; cb < 20; ++cb) {
        float4 vn[4];
        if (cb < 19) {
            #pragma unroll
            for (int j = 0; j < 4; ++j) vn[j] = p4[(size_t)(9 + cb * 4 + j) * HW4];
        }
        #pragma unroll
        for (int j = 0; j < 4; ++j) {
            const int c = cb * 4 + j;          // strict > == first-max (jnp.argmax)
            if (vb[j].x > best.x) { best.x = vb[j].x; bx = c; }
            if (vb[j].y > best.y) { best.y = vb[j].y; by = c; }
            if (vb[j].z > best.z) { best.z = vb[j].z; bz = c; }
            if (vb[j].w > best.w) { best.w = vb[j].w; bw4 = c; }
        }
        #pragma unroll
        for (int j = 0; j < 4; ++j) vb[j] = vn[j];
    }

    const float aw = anch[2 * a], ah = anch[2 * a + 1];
    const int i0 = base + a * HW + hw;
    float* o = boxesAll + ((size_t)b * NCAND + i0) * 6;
    {
        const int h = hw / Hdim, w = hw - h * Hdim;
        decode_write(o, w, h, ts, txv.x, tyv.x, twv.x, thv.x, xov.x, aw, ah, bx);
    }
    {
        const int h = (hw + 1) / Hdim, w = (hw + 1) - h * Hdim;
        decode_write(o + 6, w, h, ts, txv.y, tyv.y, twv.y, thv.y, xov.y, aw, ah, by);
    }
    {
        const int h = (hw + 2) / Hdim, w = (hw + 2) - h * Hdim;
        decode_write(o + 12, w, h, ts, txv.z, tyv.z, twv.z, thv.z, xov.z, aw, ah, bz);
    }
    {
        const int h = (hw + 3) / Hdim, w = (hw + 3) - h * Hdim;
        decode_write(o + 18, w, h, ts, txv.w, tyv.w, twv.w, thv.w, xov.w, aw, ah, bw4);
    }
}

// ---------------------------------------------------------------------------
// Fused kernel, 512-thread blocks:
//   blocks [0,B):            per-image top-512 radix select (exact)
//   blocks [B, B+DECB*B):    streaming float4/scalar decode of all candidates
// ---------------------------------------------------------------------------
__global__ __launch_bounds__(512, 2) void main_kernel(
    const float* __restrict__ in13,
    const float* __restrict__ in26,
    const float* __restrict__ in52,
    const float* __restrict__ a13,
    const float* __restrict__ a26,
    const float* __restrict__ a52,
    int B,
    int* __restrict__ selidx,
    int* __restrict__ selv,
    float* __restrict__ boxesAll)
{
    __shared__ __align__(16) char smem_raw[sizeof(SelShared)];
    const int bid = blockIdx.x;
    const int tid = threadIdx.x;

    if (bid < B) {
        // ================= SELECT (one block per image) =================
        SelShared& S = *reinterpret_cast<SelShared*>(smem_raw);
        const int b = bid;
        if (tid == 0) { S.cnt = 0; S.prefix = 0; S.krem = KSEL; S.shift = 52; S.brk = 0; S.V = 0; }
        __syncthreads();

        for (int i = tid; i < NCAND; i += 512) {
            const unsigned long long k = cand_key(i, b, in13, in26, in52);
            const unsigned long long bal = __ballot((k >> 63) != 0ull);
            if ((tid & 63) == 0) atomicAdd(&S.V, (int)__popcll(bal));
        }
        __syncthreads();
        const bool include = (S.V < KSEL);   // degenerate fallback only

        while (true) {
            const int shift = S.shift;
            const unsigned long long prefix = S.prefix;
            const int krem = S.krem;
            __syncthreads();
            for (int i = tid; i < 4096; i += 512) S.hist[i] = 0;
            __syncthreads();
            for (int i = tid; i < NCAND; i += 512) {
                const unsigned long long k = cand_key(i, b, in13, in26, in52);
                const bool part = include || ((k >> 63) != 0ull);
                const bool ok = part &&
                    ((shift == 52) || ((k >> (shift + 12)) == prefix));
                if (ok) atomicAdd(&S.hist[(unsigned)((k >> shift) & 0xFFFull)], 1u);
            }
            __syncthreads();
            if (tid < 64) {
                unsigned int s = 0;
                for (int q = 0; q < 64; ++q) s += S.hist[tid * 64 + q];
                unsigned int suf = s;
                for (int off = 1; off < 64; off <<= 1) {
                    const unsigned int v = __shfl_down(suf, off);
                    if (tid + off < 64) suf += v;
                }
                const unsigned long long ball = __ballot(suf >= (unsigned)krem);
                const int lstar = 63 - __clzll(ball);
                const unsigned int base = (lstar < 63) ? __shfl(suf, lstar + 1) : 0u;
                const unsigned int wv = S.hist[lstar * 64 + (63 - tid)];
                unsigned int pv = wv;
                for (int off = 1; off < 64; off <<= 1) {
                    const unsigned int v = __shfl_up(pv, off);
                    if (tid >= (unsigned)off) pv += v;
                }
                const unsigned long long b2 = __ballot(base + pv >= (unsigned)krem);
                const int mstar = __ffsll(b2) - 1;
                const unsigned int pvm = __shfl(pv, mstar);
                const unsigned int wvm = __shfl(wv, mstar);
                if (tid == 0) {
                    const int dstar = lstar * 64 + (63 - mstar);
                    const unsigned long long np = (prefix << 12) | (unsigned long long)dstar;
                    const int Albl = (int)(base + pvm - wvm);
                    const int Cpool = (KSEL - krem) + Albl + (int)wvm;
                    S.prefix = np;
                    S.krem = krem - Albl;
                    if (Cpool <= POOLTGT || shift == 4) {
                        S.brk = 1;
                        S.tmin = np << shift;
                    } else {
                        S.shift = shift - 12;
                    }
                }
            }
            __syncthreads();
            if (S.brk) break;
        }
        const unsigned long long tmin = S.tmin;

        for (int i = tid; i < NCAND; i += 512) {
            const unsigned long long k = cand_key(i, b, in13, in26, in52);
            if (k >= tmin) {
                const unsigned int p = atomicAdd(&S.cnt, 1u);
                if (p < POOLCAP) S.pool[p] = k;
            }
        }
        __syncthreads();
        const int C = ((int)S.cnt < POOLCAP) ? (int)S.cnt : POOLCAP;

        for (int p = tid; p < C; p += 512) {
            const unsigned long long k = S.pool[p];
            int r = 0;
            for (int j = 0; j < C; ++j) r += (S.pool[j] > k) ? 1 : 0;
            if (r < KSEL) {
                const int idx = 0x3FFF - (int)(k & 0x3FFFull);
                selidx[(size_t)b * KSEL + r] = idx;
                selv[(size_t)b * KSEL + r]   = (int)(k >> 63);
            }
        }
        return;
    }

    // ================= DECODE =================
    const int d = bid - B;
    const int b = d / DECB;
    const int role = d - b * DECB;

    if (role < 4) {                      // s52: 2028 float4-groups over 4 blocks
        const int idx4 = role * 512 + tid;
        if (idx4 < 3 * 676) {
            const int a = idx4 / 676, g = idx4 - a * 676;
            decode4(in52, a52, b, a, g * 4, 2704, 52, 8.f, NC13 + NC26, boxesAll);
        }
    } else if (role == 4) {              // s26: 507 float4-groups, 1 block
        if (tid < 3 * 169) {
            const int a = tid / 169, g = tid - a * 169;
            decode4(in26, a26, b, a, g * 4, 676, 26, 16.f, NC13, boxesAll);
        }
    } else {                             // s13: 507 scalar, 1 block
        if (tid < NC13) {
            const int HW = 169;
            const int a = tid / HW, hw = tid - a * HW;
            const int h = hw / 13, w = hw - h * 13;
            const float* p = in13 + ((size_t)b * 255 + (size_t)a * 85) * HW + hw;
            const float tx = p[0];
            const float ty = p[(size_t)HW];
            const float tw = p[(size_t)2 * HW];
            const float th = p[(size_t)3 * HW];
            const float xo = p[(size_t)4 * HW];
            float best = -INFINITY; int bi = 0;
            float vb[4];
            #pragma unroll
            for (int j = 0; j < 4; ++j) vb[j] = p[(size_t)(5 + j) * HW];
            for (int cb = 0; cb < 20; ++cb) {
                float vn[4];
                if (cb < 19) {
                    #pragma unroll
                    for (int j = 0; j < 4; ++j) vn[j] = p[(size_t)(9 + cb * 4 + j) * HW];
                }
                #pragma unroll
                for (int j = 0; j < 4; ++j) {
                    const int c = cb * 4 + j;
                    if (vb[j] > best) { best = vb[j]; bi = c; }
                }
                #pragma unroll
                for (int j = 0; j < 4; ++j) vb[j] = vn[j];
            }
            const int i = a * HW + hw;   // base 0
            decode_write(boxesAll + ((size_t)b * NCAND + i) * 6, w, h, 32.f,
                         tx, ty, tw, th, xo, a13[2 * a], a13[2 * a + 1], bi);
        }
    }
}

// ---------------------------------------------------------------------------
// NMS kernel (unchanged from the verified version).
// ---------------------------------------------------------------------------
__global__ __launch_bounds__(512) void nms_kernel(
    const float* __restrict__ boxesAll,
    const int* __restrict__ selidx,
    const int* __restrict__ selv,
    float* __restrict__ out)
{
    __shared__ float X1[KSEL], Y1[KSEL], X2[KSEL], Y2[KSEL], AR[KSEL];
    __shared__ int CLS[KSEL];
    __shared__ unsigned int CM[80 * CMW];
    __shared__ unsigned int SUP[KSEL * SUPW];
    __shared__ unsigned int KEEP[16];
    __shared__ int shV;

    const int b = blockIdx.x;
    const int tid = threadIdx.x;

    const int n = selidx[(size_t)b * KSEL + tid];
    int base, HW;
    if (n < NC13)             { base = 0;           HW = 169; }
    else if (n < NC13 + NC26) { base = NC13;        HW = 676; }
    else                      { base = NC13 + NC26; HW = 2704; }
    const int within = n - base;
    const int hw = within / 3, a = within - 3 * hw;
    const int i = base + a * HW + hw;
    const float* src = boxesAll + ((size_t)b * NCAND + i) * 6;
    const float x1 = src[0], y1 = src[1], x2 = src[2], y2 = src[3];
    const float conf = src[4], clsf = src[5];
    const float ar = (x2 - x1) * (y2 - y1);
    const int ci = (int)clsf;
    X1[tid] = x1; Y1[tid] = y1; X2[tid] = x2; Y2[tid] = y2;
    AR[tid] = ar; CLS[tid] = ci;
    const int v = selv[(size_t)b * KSEL + tid];
    if (tid == 0) shV = 0;
    for (int q = tid; q < 80 * CMW; q += KSEL) CM[q] = 0;
    __syncthreads();

    atomicOr(&CM[ci * CMW + (tid >> 5)], 1u << (tid & 31));
    const unsigned long long bal = __ballot(v != 0);
    if ((tid & 63) == 0) atomicAdd(&shV, __popcll(bal));
    __syncthreads();

    for (int wj = 0; wj < 16; ++wj) {
        unsigned int m = CM[ci * CMW + wj];
        unsigned int bits = 0;
        while (m) {
            const int bit = __ffs(m) - 1;
            m &= m - 1;
            const int j = wj * 32 + bit;
            const float iw = fminf(x2, X2[j]) - fmaxf(x1, X1[j]);
            const float ih = fminf(y2, Y2[j]) - fmaxf(y1, Y1[j]);
            if (iw > 0.0f && ih > 0.0f) {
                const float inter = iw * ih;
                if (inter > 0.3f * (ar + AR[j] - inter + 1e-9f))
                    bits |= (1u << bit);
            }
        }
        SUP[tid * SUPW + wj] = bits;
    }
    __syncthreads();

    if (tid < 64) {
        const int V = shV;
        unsigned int keepw = 0;       // lanes 0..15 hold the 512-bit keep mask
        unsigned int buf[16];
        #pragma unroll
        for (int r = 0; r < 16; ++r)
            buf[r] = (tid < 16) ? SUP[r * SUPW + tid] : 0u;
        for (int g = 0; g < 32; ++g) {
            unsigned int nbuf[16] = {0};
            if (g < 31) {
                #pragma unroll
                for (int r = 0; r < 16; ++r)
                    nbuf[r] = (tid < 16) ? SUP[((g + 1) * 16 + r) * SUPW + tid] : 0u;
            }
            #pragma unroll
            for (int r = 0; r < 16; ++r) {
                const int ii = g * 16 + r;
                const bool anysup = __any((keepw & buf[r]) != 0u);
                const bool ki = (ii < V) && !anysup;
                if (ki && tid == (ii >> 5)) keepw |= (1u << (ii & 31));
            }
            #pragma unroll
            for (int r = 0; r < 16; ++r) buf[r] = nbuf[r];
        }
        if (tid < 16) KEEP[tid] = keepw;
    }
    __syncthreads();

    const float kf = ((KEEP[tid >> 5] >> (tid & 31)) & 1u) ? 1.0f : 0.0f;
    float* dst = out + ((size_t)b * KSEL + tid) * 7;
    dst[0] = x1; dst[1] = y1; dst[2] = x2;
    dst[3] = y2; dst[4] = conf; dst[5] = clsf;
    dst[6] = kf;
}

// ---------------------------------------------------------------------------
extern "C" void kernel_launch(void* const* d_in, const int* in_sizes, int n_in,
                              void* d_out, int out_size, void* d_ws, size_t ws_size,
                              hipStream_t stream)
{
    (void)n_in; (void)out_size; (void)ws_size;
    const float* in13 = (const float*)d_in[0];
    const float* in26 = (const float*)d_in[1];
    const float* in52 = (const float*)d_in[2];
    const float* a13  = (const float*)d_in[3];
    const float* a26  = (const float*)d_in[4];
    const float* a52  = (const float*)d_in[5];
    float* out = (float*)d_out;
    const int B = in_sizes[0] / (255 * 169);

    char* w = (char*)d_ws;
    int* selidx = (int*)w;  w += ((size_t)B * KSEL * sizeof(int) + 255) & ~(size_t)255;
    int* selv   = (int*)w;  w += ((size_t)B * KSEL * sizeof(int) + 255) & ~(size_t)255;
    float* boxesAll = (float*)w;
    w += ((size_t)B * NCAND * 6 * sizeof(float) + 255) & ~(size_t)255;

    main_kernel<<<dim3(B * (1 + DECB)), 512, 0, stream>>>(
        in13, in26, in52, a13, a26, a52, B, selidx, selv, boxesAll);
    nms_kernel<<<dim3(B), 512, 0, stream>>>(boxesAll, selidx, selv, out);
}